// Round 7
// baseline (127.488 us; speedup 1.0000x reference)
//
#include <hip/hip_runtime.h>

// Shapes (fixed by setup_inputs):
//   zs   (128,256,1024) f32     rzs (128,256,1024) f32
//   pts  (128,256,118,2) f32    best (128,118,2) f32
//   qy   (128,256,64) f32       gts (128,128,118,2) f32
//   best_gt (128,118,2) f32     mapping (128,128) i32
//   vector_dims scalar = 64

typedef float f32x4 __attribute__((ext_vector_type(4)));

namespace {
constexpr int NBLOCKS = 1024;
constexpr int NTHREADS = 512;
constexpr int STRIDE = NBLOCKS * NTHREADS;      // 524288 — compile-time
constexpr int NA4 = 128 * 256 * 64 / 4;         // 524288 = 1 * STRIDE exactly
constexpr int NB4 = 128 * 128 * 1024 / 4;       // 4194304 = 8 * STRIDE exactly
constexpr int NC4 = 128 * 128 * 59;             // 966656 float4 rows of 59
constexpr int ND4 = 128 * 59;                   // 7552
}

__global__ __launch_bounds__(512) void fused_loss(
    const float* __restrict__ zs, const float* __restrict__ rzs,
    const float* __restrict__ pts, const float* __restrict__ best,
    const float* __restrict__ qy, const float* __restrict__ gts,
    const float* __restrict__ best_gt, const int* __restrict__ mapping,
    double* __restrict__ partials, unsigned* __restrict__ counter,
    float* __restrict__ out)
{
    // XCD-chunked swizzle: each XCD's 128 blocks cover 2 complete batches ->
    // gather duplicates are L2-local instead of cross-XCD HBM re-fetches.
    const int d = blockIdx.x;
    const int w = ((d & 7) << 7) + (d >> 3);    // bijective on [0,1024)
    const int tid = w * NTHREADS + threadIdx.x;
    const float logV = 4.1588830833596715f;  // log(64)

    double accA = 0.0, accB0 = 0.0, accB1 = 0.0;
    double accC = 0.0, accCm = 0.0, accD = 0.0, accDm = 0.0;

    // ---- Segment A: KLD — one nt float4 per thread ----
    {
        const f32x4* qy4 = reinterpret_cast<const f32x4*>(qy);
        f32x4 q = __builtin_nontemporal_load(qy4 + tid);
        float s = q.x * (logf(q.x + 1e-20f) + logV)
                + q.y * (logf(q.y + 1e-20f) + logV)
                + q.z * (logf(q.z + 1e-20f) + logV)
                + q.w * (logf(q.w + 1e-20f) + logV);
        accA = (double)s;
    }

    // ---- Segment C (short, latency-bound) before B so its loads overlap ----
    {
        const f32x4* pts4 = reinterpret_cast<const f32x4*>(pts);
        const f32x4* gts4 = reinterpret_cast<const f32x4*>(gts);
#pragma unroll
        for (int k = 0; k < 2; ++k) {
            int idx = tid + k * STRIDE;
            if (idx < NC4) {
                unsigned row = (unsigned)idx / 59u;   // b*128 + i
                int j = idx - (int)row * 59;          // float4 idx: points 2j, 2j+1
                int b = (int)(row >> 7);
                int m = mapping[row];
                f32x4 pt = pts4[((b << 8) + m) * 59 + j];
                f32x4 g  = __builtin_nontemporal_load(gts4 + (int)row * 59 + j);
                float dx = pt.x - g.x, dy = pt.y - g.y;
                float dz = pt.z - g.z, dw = pt.w - g.w;
                float sq_lo = dx * dx + dy * dy;      // point 2j
                float sq_hi = dz * dz + dw * dw;      // point 2j+1
                accC += (double)(sq_lo + sq_hi);
                if (j == 0 || j == 44) accCm += (double)sq_lo;   // points 0, 88
                if (j == 14 || j == 58) accCm += (double)sq_hi;  // points 29, 117
            }
        }
    }

    // ---- Segment D (tiny) ----
    if (tid < ND4) {
        const f32x4* best4 = reinterpret_cast<const f32x4*>(best);
        const f32x4* bgt4  = reinterpret_cast<const f32x4*>(best_gt);
        unsigned bi = (unsigned)tid / 59u;
        int j = tid - (int)bi * 59;
        f32x4 pb = best4[tid];
        f32x4 g  = bgt4[tid];
        float dx = pb.x - g.x, dy = pb.y - g.y;
        float dz = pb.z - g.z, dw = pb.w - g.w;
        float sq_lo = dx * dx + dy * dy;
        float sq_hi = dz * dz + dw * dw;
        accD = (double)(sq_lo + sq_hi);
        if (j == 0 || j == 44) accDm += (double)sq_lo;
        if (j == 14 || j == 58) accDm += (double)sq_hi;
    }

    // ---- Segment B: ae = mse(rzs[b,map[b,i],:], zs[b,i,:]) — 8 iters ----
    {
        const f32x4* rzs4 = reinterpret_cast<const f32x4*>(rzs);
        const f32x4* zs4  = reinterpret_cast<const f32x4*>(zs);
#pragma unroll
        for (int k = 0; k < 8; ++k) {
            int idx = tid + k * STRIDE;     // < NB4 always (exact multiple)
            int off = idx & 255;            // float4 offset within D=1024 row
            int row = idx >> 8;             // b*128 + i  (wave-uniform)
            int b   = row >> 7;
            int m   = mapping[row];
            f32x4 r = rzs4[(((b << 8) + m) << 8) + off];
            f32x4 z = __builtin_nontemporal_load(
                          zs4 + (((size_t)(row + (b << 7))) << 8) + off);
            float dx = r.x - z.x, dy = r.y - z.y, dz = r.z - z.z, dw = r.w - z.w;
            double s = (double)(dx * dx + dy * dy + dz * dz + dw * dw);
            if (k & 1) accB1 += s; else accB0 += s;
        }
    }

    // weights: kld 1/(B*S), ae 1/(B*Sg*D), bias 1/(B*Sg*P*2) + 10/(B*Sg*8),
    //          best 1/(B*P*2) + 10/(B*8)
    double total = accA  * (1.0 / 32768.0)
                 + (accB0 + accB1) * (1.0 / 16777216.0)
                 + accC  * (1.0 / 3866624.0)
                 + accCm * (10.0 / 131072.0)
                 + accD  * (1.0 / 30208.0)
                 + accDm * (10.0 / 1024.0);

    // ---- block reduce (wave shfl + LDS) ----
    for (int off = 32; off > 0; off >>= 1)
        total += __shfl_down(total, off, 64);
    __shared__ double wsum[8];
    __shared__ int lastFlag;
    int lane = threadIdx.x & 63;
    int wid  = threadIdx.x >> 6;
    if (lane == 0) wsum[wid] = total;
    __syncthreads();

    // ---- last-block-done: store partial, release, count; last block sums ----
    if (threadIdx.x == 0) {
        double t = wsum[0] + wsum[1] + wsum[2] + wsum[3]
                 + wsum[4] + wsum[5] + wsum[6] + wsum[7];
        partials[blockIdx.x] = t;
        __threadfence();  // release: partial visible device-wide before count
        unsigned old = __hip_atomic_fetch_add(counter, 1u, __ATOMIC_ACQ_REL,
                                              __HIP_MEMORY_SCOPE_AGENT);
        lastFlag = (old == (unsigned)(NBLOCKS - 1));
    }
    __syncthreads();

    if (lastFlag) {
        __threadfence();  // acquire: invalidate L1/L2 so partials are fresh
        double t = partials[threadIdx.x] + partials[threadIdx.x + 512];
        for (int off = 32; off > 0; off >>= 1)
            t += __shfl_down(t, off, 64);
        __syncthreads();            // all reads of wsum done; safe to reuse
        if (lane == 0) wsum[wid] = t;
        __syncthreads();
        if (threadIdx.x == 0)
            out[0] = (float)(wsum[0] + wsum[1] + wsum[2] + wsum[3]
                           + wsum[4] + wsum[5] + wsum[6] + wsum[7]);
    }
}

extern "C" void kernel_launch(void* const* d_in, const int* in_sizes, int n_in,
                              void* d_out, int out_size, void* d_ws, size_t ws_size,
                              hipStream_t stream) {
    const float* zs      = (const float*)d_in[0];
    const float* rzs     = (const float*)d_in[1];
    const float* pts     = (const float*)d_in[2];
    const float* best    = (const float*)d_in[3];
    const float* qy      = (const float*)d_in[4];
    const float* gts     = (const float*)d_in[5];
    const float* best_gt = (const float*)d_in[6];
    const int*   mapping = (const int*)d_in[7];

    // ws layout: [0, 8192) partials (1024 f64), [8192, 8196) counter
    double*   partials = (double*)d_ws;
    unsigned* counter  = (unsigned*)((char*)d_ws + NBLOCKS * sizeof(double));

    hipMemsetAsync(counter, 0, sizeof(unsigned), stream);
    fused_loss<<<NBLOCKS, NTHREADS, 0, stream>>>(zs, rzs, pts, best, qy, gts,
                                                 best_gt, mapping, partials,
                                                 counter, (float*)d_out);
}

// Round 8
// 39.447 us; speedup vs baseline: 3.2318x; 3.2318x over previous
//
#include <hip/hip_runtime.h>

// Shapes (fixed by setup_inputs):
//   zs   (128,256,1024) f32     rzs (128,256,1024) f32
//   pts  (128,256,118,2) f32    best (128,118,2) f32
//   qy   (128,256,64) f32       gts (128,128,118,2) f32
//   best_gt (128,118,2) f32     mapping (128,128) i32
//   vector_dims scalar = 64

typedef float f32x4 __attribute__((ext_vector_type(4)));

namespace {
constexpr int NBLOCKS = 1024;
constexpr int NTHREADS = 512;
constexpr int STRIDE = NBLOCKS * NTHREADS;      // 524288 — compile-time
constexpr int NA4 = 128 * 256 * 64 / 4;         // 524288 = 1 * STRIDE exactly
constexpr int NB4 = 128 * 128 * 1024 / 4;       // 4194304 = 8 * STRIDE exactly
constexpr int NC4 = 128 * 128 * 59;             // 966656 float4 rows of 59
constexpr int ND4 = 128 * 59;                   // 7552
}

__global__ __launch_bounds__(512) void fused_loss(
    const float* __restrict__ zs, const float* __restrict__ rzs,
    const float* __restrict__ pts, const float* __restrict__ best,
    const float* __restrict__ qy, const float* __restrict__ gts,
    const float* __restrict__ best_gt, const int* __restrict__ mapping,
    double* __restrict__ partials, unsigned* __restrict__ counter,
    float* __restrict__ out)
{
    // XCD-chunked swizzle: each XCD's 128 blocks cover 2 complete batches ->
    // gather duplicates are L2-local instead of cross-XCD HBM re-fetches.
    const int d = blockIdx.x;
    const int w = ((d & 7) << 7) + (d >> 3);    // bijective on [0,1024)
    const int tid = w * NTHREADS + threadIdx.x;
    const float logV = 4.1588830833596715f;  // log(64)

    double accA = 0.0, accB0 = 0.0, accB1 = 0.0;
    double accC = 0.0, accCm = 0.0, accD = 0.0, accDm = 0.0;

    // ---- Segment A: KLD — one nt float4 per thread ----
    {
        const f32x4* qy4 = reinterpret_cast<const f32x4*>(qy);
        f32x4 q = __builtin_nontemporal_load(qy4 + tid);
        float s = q.x * (logf(q.x + 1e-20f) + logV)
                + q.y * (logf(q.y + 1e-20f) + logV)
                + q.z * (logf(q.z + 1e-20f) + logV)
                + q.w * (logf(q.w + 1e-20f) + logV);
        accA = (double)s;
    }

    // ---- Segment C (short, latency-bound) before B so its loads overlap ----
    {
        const f32x4* pts4 = reinterpret_cast<const f32x4*>(pts);
        const f32x4* gts4 = reinterpret_cast<const f32x4*>(gts);
#pragma unroll
        for (int k = 0; k < 2; ++k) {
            int idx = tid + k * STRIDE;
            if (idx < NC4) {
                unsigned row = (unsigned)idx / 59u;   // b*128 + i
                int j = idx - (int)row * 59;          // float4 idx: points 2j, 2j+1
                int b = (int)(row >> 7);
                int m = mapping[row];
                f32x4 pt = pts4[((b << 8) + m) * 59 + j];
                f32x4 g  = __builtin_nontemporal_load(gts4 + (int)row * 59 + j);
                float dx = pt.x - g.x, dy = pt.y - g.y;
                float dz = pt.z - g.z, dw = pt.w - g.w;
                float sq_lo = dx * dx + dy * dy;      // point 2j
                float sq_hi = dz * dz + dw * dw;      // point 2j+1
                accC += (double)(sq_lo + sq_hi);
                if (j == 0 || j == 44) accCm += (double)sq_lo;   // points 0, 88
                if (j == 14 || j == 58) accCm += (double)sq_hi;  // points 29, 117
            }
        }
    }

    // ---- Segment D (tiny) ----
    if (tid < ND4) {
        const f32x4* best4 = reinterpret_cast<const f32x4*>(best);
        const f32x4* bgt4  = reinterpret_cast<const f32x4*>(best_gt);
        unsigned bi = (unsigned)tid / 59u;
        int j = tid - (int)bi * 59;
        f32x4 pb = best4[tid];
        f32x4 g  = bgt4[tid];
        float dx = pb.x - g.x, dy = pb.y - g.y;
        float dz = pb.z - g.z, dw = pb.w - g.w;
        float sq_lo = dx * dx + dy * dy;
        float sq_hi = dz * dz + dw * dw;
        accD = (double)(sq_lo + sq_hi);
        if (j == 0 || j == 44) accDm += (double)sq_lo;
        if (j == 14 || j == 58) accDm += (double)sq_hi;
    }

    // ---- Segment B: ae = mse(rzs[b,map[b,i],:], zs[b,i,:]) — 8 iters ----
    {
        const f32x4* rzs4 = reinterpret_cast<const f32x4*>(rzs);
        const f32x4* zs4  = reinterpret_cast<const f32x4*>(zs);
#pragma unroll
        for (int k = 0; k < 8; ++k) {
            int idx = tid + k * STRIDE;     // < NB4 always (exact multiple)
            int off = idx & 255;            // float4 offset within D=1024 row
            int row = idx >> 8;             // b*128 + i  (wave-uniform)
            int b   = row >> 7;
            int m   = mapping[row];
            f32x4 r = rzs4[(((b << 8) + m) << 8) + off];
            f32x4 z = __builtin_nontemporal_load(
                          zs4 + (((size_t)(row + (b << 7))) << 8) + off);
            float dx = r.x - z.x, dy = r.y - z.y, dz = r.z - z.z, dw = r.w - z.w;
            double s = (double)(dx * dx + dy * dy + dz * dz + dw * dw);
            if (k & 1) accB1 += s; else accB0 += s;
        }
    }

    // weights: kld 1/(B*S), ae 1/(B*Sg*D), bias 1/(B*Sg*P*2) + 10/(B*Sg*8),
    //          best 1/(B*P*2) + 10/(B*8)
    double total = accA  * (1.0 / 32768.0)
                 + (accB0 + accB1) * (1.0 / 16777216.0)
                 + accC  * (1.0 / 3866624.0)
                 + accCm * (10.0 / 131072.0)
                 + accD  * (1.0 / 30208.0)
                 + accDm * (10.0 / 1024.0);

    // ---- block reduce (wave shfl + LDS) ----
    for (int off = 32; off > 0; off >>= 1)
        total += __shfl_down(total, off, 64);
    __shared__ double wsum[8];
    __shared__ int lastFlag;
    int lane = threadIdx.x & 63;
    int wid  = threadIdx.x >> 6;
    if (lane == 0) wsum[wid] = total;
    __syncthreads();

    // ---- last-block-done, fence-free: all cross-XCD traffic is MALL RMWs ----
    if (threadIdx.x == 0) {
        double t = wsum[0] + wsum[1] + wsum[2] + wsum[3]
                 + wsum[4] + wsum[5] + wsum[6] + wsum[7];
        // RMW executes at the coherence point (MALL) — no L2 writeback needed.
        __hip_atomic_exchange(&partials[d], t, __ATOMIC_RELAXED,
                              __HIP_MEMORY_SCOPE_AGENT);
        // Ensure the exchange is globally performed before we count ourselves.
        asm volatile("s_waitcnt vmcnt(0)" ::: "memory");
        unsigned old = __hip_atomic_fetch_add(counter, 1u, __ATOMIC_RELAXED,
                                              __HIP_MEMORY_SCOPE_AGENT);
        lastFlag = (old == (unsigned)(NBLOCKS - 1));
    }
    __syncthreads();

    if (lastFlag) {
        // Read partials via +0.0 RMWs: performed at MALL, always fresh.
        double t = __hip_atomic_fetch_add(&partials[threadIdx.x], 0.0,
                                          __ATOMIC_RELAXED,
                                          __HIP_MEMORY_SCOPE_AGENT)
                 + __hip_atomic_fetch_add(&partials[threadIdx.x + 512], 0.0,
                                          __ATOMIC_RELAXED,
                                          __HIP_MEMORY_SCOPE_AGENT);
        for (int off = 32; off > 0; off >>= 1)
            t += __shfl_down(t, off, 64);
        __syncthreads();            // all prior reads of wsum done; reuse it
        if (lane == 0) wsum[wid] = t;
        __syncthreads();
        if (threadIdx.x == 0)
            out[0] = (float)(wsum[0] + wsum[1] + wsum[2] + wsum[3]
                           + wsum[4] + wsum[5] + wsum[6] + wsum[7]);
    }
}

extern "C" void kernel_launch(void* const* d_in, const int* in_sizes, int n_in,
                              void* d_out, int out_size, void* d_ws, size_t ws_size,
                              hipStream_t stream) {
    const float* zs      = (const float*)d_in[0];
    const float* rzs     = (const float*)d_in[1];
    const float* pts     = (const float*)d_in[2];
    const float* best    = (const float*)d_in[3];
    const float* qy      = (const float*)d_in[4];
    const float* gts     = (const float*)d_in[5];
    const float* best_gt = (const float*)d_in[6];
    const int*   mapping = (const int*)d_in[7];

    // ws layout: [0, 8192) partials (1024 f64), [8192, 8196) counter
    double*   partials = (double*)d_ws;
    unsigned* counter  = (unsigned*)((char*)d_ws + NBLOCKS * sizeof(double));

    hipMemsetAsync(counter, 0, sizeof(unsigned), stream);
    fused_loss<<<NBLOCKS, NTHREADS, 0, stream>>>(zs, rzs, pts, best, qy, gts,
                                                 best_gt, mapping, partials,
                                                 counter, (float*)d_out);
}

// Round 9
// 32.397 us; speedup vs baseline: 3.9351x; 1.2176x over previous
//
#include <hip/hip_runtime.h>

// Shapes (fixed by setup_inputs):
//   zs   (128,256,1024) f32     rzs (128,256,1024) f32
//   pts  (128,256,118,2) f32    best (128,118,2) f32
//   qy   (128,256,64) f32       gts (128,128,118,2) f32
//   best_gt (128,118,2) f32     mapping (128,128) i32
//   vector_dims scalar = 64
//
// Structure notes (validated over rounds 1-8):
//  - Two kernels. Single-kernel tail reduction LOSES on MI355X:
//    per-block device-scope fences cost ~100µs aggregate (R7), and even
//    fence-free MALL-RMW tails cost ~8µs (R8) vs ~2-3µs kernel boundary.
//  - One f64 partial per block (R2: single-address atomicAdd serialized,
//    +24µs).
//  - XCD-chunked swizzle so each XCD's 128 blocks cover 2 whole batches:
//    gather duplicates become L2-local (R6: -1.8µs).

typedef float f32x4 __attribute__((ext_vector_type(4)));

namespace {
constexpr int NBLOCKS = 1024;
constexpr int NTHREADS = 512;
constexpr int STRIDE = NBLOCKS * NTHREADS;      // 524288 — compile-time
constexpr int NA4 = 128 * 256 * 64 / 4;         // 524288 = 1 * STRIDE exactly
constexpr int NB4 = 128 * 128 * 1024 / 4;       // 4194304 = 8 * STRIDE exactly
constexpr int NC4 = 128 * 128 * 59;             // 966656 float4 rows of 59
constexpr int ND4 = 128 * 59;                   // 7552
}

__global__ __launch_bounds__(512) void fused_loss(
    const float* __restrict__ zs, const float* __restrict__ rzs,
    const float* __restrict__ pts, const float* __restrict__ best,
    const float* __restrict__ qy, const float* __restrict__ gts,
    const float* __restrict__ best_gt, const int* __restrict__ mapping,
    double* __restrict__ partials)
{
    const int d = blockIdx.x;
    const int w = ((d & 7) << 7) + (d >> 3);    // bijective on [0,1024)
    const int tid = w * NTHREADS + threadIdx.x;
    const float logV = 4.1588830833596715f;  // log(64)

    double accA = 0.0, accB0 = 0.0, accB1 = 0.0;
    double accC = 0.0, accCm = 0.0, accD = 0.0, accDm = 0.0;

    // ---- Segment A: KLD — one nt float4 per thread ----
    {
        const f32x4* qy4 = reinterpret_cast<const f32x4*>(qy);
        f32x4 q = __builtin_nontemporal_load(qy4 + tid);
        float s = q.x * (logf(q.x + 1e-20f) + logV)
                + q.y * (logf(q.y + 1e-20f) + logV)
                + q.z * (logf(q.z + 1e-20f) + logV)
                + q.w * (logf(q.w + 1e-20f) + logV);
        accA = (double)s;
    }

    // ---- Segment C (short, latency-bound) before B so its loads overlap ----
    {
        const f32x4* pts4 = reinterpret_cast<const f32x4*>(pts);
        const f32x4* gts4 = reinterpret_cast<const f32x4*>(gts);
#pragma unroll
        for (int k = 0; k < 2; ++k) {
            int idx = tid + k * STRIDE;
            if (idx < NC4) {
                unsigned row = (unsigned)idx / 59u;   // b*128 + i
                int j = idx - (int)row * 59;          // float4 idx: points 2j, 2j+1
                int b = (int)(row >> 7);
                int m = mapping[row];
                f32x4 pt = pts4[((b << 8) + m) * 59 + j];
                f32x4 g  = __builtin_nontemporal_load(gts4 + (int)row * 59 + j);
                float dx = pt.x - g.x, dy = pt.y - g.y;
                float dz = pt.z - g.z, dw = pt.w - g.w;
                float sq_lo = dx * dx + dy * dy;      // point 2j
                float sq_hi = dz * dz + dw * dw;      // point 2j+1
                accC += (double)(sq_lo + sq_hi);
                if (j == 0 || j == 44) accCm += (double)sq_lo;   // points 0, 88
                if (j == 14 || j == 58) accCm += (double)sq_hi;  // points 29, 117
            }
        }
    }

    // ---- Segment D (tiny) ----
    if (tid < ND4) {
        const f32x4* best4 = reinterpret_cast<const f32x4*>(best);
        const f32x4* bgt4  = reinterpret_cast<const f32x4*>(best_gt);
        unsigned bi = (unsigned)tid / 59u;
        int j = tid - (int)bi * 59;
        f32x4 pb = best4[tid];
        f32x4 g  = bgt4[tid];
        float dx = pb.x - g.x, dy = pb.y - g.y;
        float dz = pb.z - g.z, dw = pb.w - g.w;
        float sq_lo = dx * dx + dy * dy;
        float sq_hi = dz * dz + dw * dw;
        accD = (double)(sq_lo + sq_hi);
        if (j == 0 || j == 44) accDm += (double)sq_lo;
        if (j == 14 || j == 58) accDm += (double)sq_hi;
    }

    // ---- Segment B: ae = mse(rzs[b,map[b,i],:], zs[b,i,:]) — 8 iters ----
    {
        const f32x4* rzs4 = reinterpret_cast<const f32x4*>(rzs);
        const f32x4* zs4  = reinterpret_cast<const f32x4*>(zs);
#pragma unroll
        for (int k = 0; k < 8; ++k) {
            int idx = tid + k * STRIDE;     // < NB4 always (exact multiple)
            int off = idx & 255;            // float4 offset within D=1024 row
            int row = idx >> 8;             // b*128 + i  (wave-uniform)
            int b   = row >> 7;
            int m   = mapping[row];
            f32x4 r = rzs4[(((b << 8) + m) << 8) + off];
            f32x4 z = __builtin_nontemporal_load(
                          zs4 + (((size_t)(row + (b << 7))) << 8) + off);
            float dx = r.x - z.x, dy = r.y - z.y, dz = r.z - z.z, dw = r.w - z.w;
            double s = (double)(dx * dx + dy * dy + dz * dz + dw * dw);
            if (k & 1) accB1 += s; else accB0 += s;
        }
    }

    // weights: kld 1/(B*S), ae 1/(B*Sg*D), bias 1/(B*Sg*P*2) + 10/(B*Sg*8),
    //          best 1/(B*P*2) + 10/(B*8)
    double total = accA  * (1.0 / 32768.0)
                 + (accB0 + accB1) * (1.0 / 16777216.0)
                 + accC  * (1.0 / 3866624.0)
                 + accCm * (10.0 / 131072.0)
                 + accD  * (1.0 / 30208.0)
                 + accDm * (10.0 / 1024.0);

    // ---- block reduce (wave shfl + LDS), one plain store per block ----
    for (int off = 32; off > 0; off >>= 1)
        total += __shfl_down(total, off, 64);
    __shared__ double wsum[8];
    int lane = threadIdx.x & 63;
    int wid  = threadIdx.x >> 6;
    if (lane == 0) wsum[wid] = total;
    __syncthreads();
    if (threadIdx.x == 0) {
        double t = wsum[0] + wsum[1] + wsum[2] + wsum[3]
                 + wsum[4] + wsum[5] + wsum[6] + wsum[7];
        partials[blockIdx.x] = t;   // order irrelevant to the sum
    }
}

__global__ __launch_bounds__(256) void finalize(
    const double* __restrict__ partials, float* __restrict__ out)
{
    double t = 0.0;
#pragma unroll
    for (int k = 0; k < 4; ++k)
        t += partials[threadIdx.x + k * 256];
    for (int off = 32; off > 0; off >>= 1)
        t += __shfl_down(t, off, 64);
    __shared__ double wsum[4];
    int lane = threadIdx.x & 63;
    int wid  = threadIdx.x >> 6;
    if (lane == 0) wsum[wid] = t;
    __syncthreads();
    if (threadIdx.x == 0)
        out[0] = (float)(wsum[0] + wsum[1] + wsum[2] + wsum[3]);
}

extern "C" void kernel_launch(void* const* d_in, const int* in_sizes, int n_in,
                              void* d_out, int out_size, void* d_ws, size_t ws_size,
                              hipStream_t stream) {
    const float* zs      = (const float*)d_in[0];
    const float* rzs     = (const float*)d_in[1];
    const float* pts     = (const float*)d_in[2];
    const float* best    = (const float*)d_in[3];
    const float* qy      = (const float*)d_in[4];
    const float* gts     = (const float*)d_in[5];
    const float* best_gt = (const float*)d_in[6];
    const int*   mapping = (const int*)d_in[7];

    double* partials = (double*)d_ws;  // 1024 doubles, written unconditionally

    fused_loss<<<NBLOCKS, NTHREADS, 0, stream>>>(zs, rzs, pts, best, qy, gts,
                                                 best_gt, mapping, partials);
    finalize<<<1, 256, 0, stream>>>(partials, (float*)d_out);
}